// Round 7
// baseline (456.408 us; speedup 1.0000x reference)
//
#include <hip/hip_runtime.h>
#include <math.h>

#define D_MODEL 1024
#define NUM_HEADS 16
#define DK 64
#define BATCH 2
#define NSEQ 2048
#define MROWS (BATCH * NSEQ)   // 4096

typedef __attribute__((ext_vector_type(8))) short bf16x8;
typedef __attribute__((ext_vector_type(4))) short s16x4;
typedef __attribute__((ext_vector_type(4))) float f32x4;
typedef unsigned short u16;

static __device__ __forceinline__ u16 f2bf_rne(float x) {
    union { float f; unsigned u; } v; v.f = x;
    unsigned r = v.u + 0x7fffu + ((v.u >> 16) & 1u);
    return (u16)(r >> 16);
}
static __device__ __forceinline__ void split_bf16(float x, u16& hi, u16& lo) {
    union { float f; unsigned u; } v; v.f = x;
    unsigned hb = v.u & 0xffff0000u;
    hi = (u16)(hb >> 16);
    union { unsigned u; float f; } hv; hv.u = hb;
    lo = f2bf_rne(x - hv.f);
}

// ---------------------------------------------------------------------------
// fp32 -> split bf16 planes, 4 tensors per launch (weights only now).
// ---------------------------------------------------------------------------
struct SplitN { const float* src[4]; u16* h[4]; u16* l[4]; };
__global__ __launch_bounds__(256)
void split_multi(SplitN args, int n8)
{
    const int w = blockIdx.y;
    const int i = blockIdx.x * 256 + threadIdx.x;
    if (i >= n8) return;
    const float* src = args.src[w];
    float4 a = ((const float4*)src)[2 * i];
    float4 b = ((const float4*)src)[2 * i + 1];
    float x[8] = {a.x, a.y, a.z, a.w, b.x, b.y, b.z, b.w};
    u16 hh[8], ll[8];
#pragma unroll
    for (int j = 0; j < 8; ++j) split_bf16(x[j], hh[j], ll[j]);
    *(uint4*)(args.h[w] + 8 * (size_t)i) = *(uint4*)hh;
    *(uint4*)(args.l[w] + 8 * (size_t)i) = *(uint4*)ll;
}

// ---------------------------------------------------------------------------
// MFMA GEMM v3, split-bf16 3-term: C = (A @ W^T + bias) * scale.
// A read as FP32 directly (split fused into staging); W as pre-split planes.
// MT=4: BM=128; MT=2: BM=64. BN=128, BK=32, 256 thr (4 waves 2x2),
// wave tile (MT*16)x64. Register-prefetch pipeline: loads for tile k+1
// issued right after the post-write barrier -> in flight during MFMA phase.
// LDS single-buffered, swizzled 16B granules: slot = g ^ (r&3) ^ ((r>>2)&3)
// -> 2-way max on writes and fragment reads (free).
// Grid: blockIdx.x = M dim (same-A blocks share an XCD), y = N, z = batch.
// mode 0: fp32 out. mode 1: split planes. mode 2 (MT=4): V -> per-head
// transposed single RNE plane Vt[b][h][d][n] via LDS re-transpose.
// ---------------------------------------------------------------------------
struct GemmDesc {
    const float* Af;
    const u16 *Wh, *Wl;
    const float* bias;
    float* outF;
    u16 *outH, *outL;
    float scale;
    int mode;
};
struct GemmBatch { GemmDesc d[3]; };

template<int MT>
__global__ __launch_bounds__(256)
void gemm_v3(GemmBatch batch, int M, int N, int K)
{
    constexpr int BM = MT * 32;
    __shared__ u16 SM[(2 * BM + 2 * 128) * 32];
    u16* As_h = SM;
    u16* As_l = As_h + BM * 32;
    u16* Ws_h = As_l + BM * 32;
    u16* Ws_l = Ws_h + 128 * 32;

    const GemmDesc d = batch.d[blockIdx.z];
    const int tid  = threadIdx.x;
    const int wv   = tid >> 6, lane = tid & 63;
    const int quad = lane >> 4, lcol = lane & 15;
    const int bm = blockIdx.x * BM, bn = blockIdx.y * 128;
    const int wm = (wv >> 1) * (MT * 16), wn = (wv & 1) * 64;

    // A staging coords: MT=4 -> (row, 2-granule half); MT=2 -> (row, granule)
    int asr, ash;
    if constexpr (MT == 4) { asr = tid >> 1; ash = tid & 1; }
    else                   { asr = tid >> 2; ash = tid & 3; }
    const int mA = (asr & 3) ^ ((asr >> 2) & 3);
    const int wsr = tid >> 1, wsh = tid & 1;
    const int mW = (wsr & 3) ^ ((wsr >> 2) & 3);

    const float* Ap  = d.Af + (size_t)(bm + asr) * K;
    const u16*   Whp = d.Wh + (size_t)(bn + wsr) * K;
    const u16*   Wlp = d.Wl + (size_t)(bn + wsr) * K;

    float4 Ar[MT];
    uint4  Wrh[2], Wrl[2];

    auto loadT = [&](int k0) {
        if constexpr (MT == 4) {
            const float4* ap = (const float4*)(Ap + k0 + ash * 16);
#pragma unroll
            for (int i = 0; i < 4; ++i) Ar[i] = ap[i];
        } else {
            const float4* ap = (const float4*)(Ap + k0 + ash * 8);
            Ar[0] = ap[0]; Ar[1] = ap[1];
        }
        const uint4* wph = (const uint4*)(Whp + k0 + wsh * 16);
        const uint4* wpl = (const uint4*)(Wlp + k0 + wsh * 16);
        Wrh[0] = wph[0]; Wrh[1] = wph[1];
        Wrl[0] = wpl[0]; Wrl[1] = wpl[1];
    };

    auto storeT = [&]() {
        const float* af = (const float*)Ar;
        if constexpr (MT == 4) {
            u16 h[16], l[16];
#pragma unroll
            for (int t = 0; t < 16; ++t) split_bf16(af[t], h[t], l[t]);
            u16* dh = As_h + asr * 32 + ((ash ^ (mA >> 1)) << 4);
            u16* dl = As_l + asr * 32 + ((ash ^ (mA >> 1)) << 4);
            const int o0 = (mA & 1) * 8, o1 = o0 ^ 8;
            *(uint4*)(dh + o0) = *(uint4*)(h + 0);
            *(uint4*)(dh + o1) = *(uint4*)(h + 8);
            *(uint4*)(dl + o0) = *(uint4*)(l + 0);
            *(uint4*)(dl + o1) = *(uint4*)(l + 8);
        } else {
            u16 h[8], l[8];
#pragma unroll
            for (int t = 0; t < 8; ++t) split_bf16(af[t], h[t], l[t]);
            const int s = 2 * ((ash >> 1) ^ (mA >> 1)) + ((ash & 1) ^ (mA & 1));
            *(uint4*)(As_h + asr * 32 + s * 8) = *(uint4*)h;
            *(uint4*)(As_l + asr * 32 + s * 8) = *(uint4*)l;
        }
        u16* dh = Ws_h + wsr * 32 + ((wsh ^ (mW >> 1)) << 4);
        u16* dl = Ws_l + wsr * 32 + ((wsh ^ (mW >> 1)) << 4);
        const int o0 = (mW & 1) * 8, o1 = o0 ^ 8;
        *(uint4*)(dh + o0) = Wrh[0];
        *(uint4*)(dh + o1) = Wrh[1];
        *(uint4*)(dl + o0) = Wrl[0];
        *(uint4*)(dl + o1) = Wrl[1];
    };

    // fragment-read slot (granule = quad), rows have (r&15) == lcol
    const int mm = (lcol & 3) ^ ((lcol >> 2) & 3);
    const int sF = (2 * ((quad >> 1) ^ (mm >> 1)) + ((quad & 1) ^ (mm & 1))) * 8;

    f32x4 acc[MT][4];
#pragma unroll
    for (int i = 0; i < MT; ++i)
#pragma unroll
        for (int j = 0; j < 4; ++j) acc[i][j] = (f32x4){0.f, 0.f, 0.f, 0.f};

    loadT(0);
    const int KT = K / 32;
    for (int kt = 0; kt < KT; ++kt) {
        if (kt) __syncthreads();           // all waves done reading prev tile
        storeT();                          // split + ds_write tile kt
        __syncthreads();                   // writes visible
        if (kt + 1 < KT) loadT((kt + 1) * 32);   // prefetch: in flight during MFMA

        bf16x8 bh[4], bl[4];
#pragma unroll
        for (int j = 0; j < 4; ++j) {
            const int off = (wn + (j << 4) + lcol) * 32 + sF;
            bh[j] = *(const bf16x8*)(Ws_h + off);
            bl[j] = *(const bf16x8*)(Ws_l + off);
        }
#pragma unroll
        for (int i = 0; i < MT; ++i) {
            const int off = (wm + (i << 4) + lcol) * 32 + sF;
            bf16x8 ah = *(const bf16x8*)(As_h + off);
            bf16x8 al = *(const bf16x8*)(As_l + off);
#pragma unroll
            for (int j = 0; j < 4; ++j) {
                acc[i][j] = __builtin_amdgcn_mfma_f32_16x16x32_bf16(ah, bh[j], acc[i][j], 0, 0, 0);
                acc[i][j] = __builtin_amdgcn_mfma_f32_16x16x32_bf16(al, bh[j], acc[i][j], 0, 0, 0);
                acc[i][j] = __builtin_amdgcn_mfma_f32_16x16x32_bf16(ah, bl[j], acc[i][j], 0, 0, 0);
            }
        }
    }

    if constexpr (MT == 4) {
        if (batch.d[blockIdx.z].mode == 2) {
            // V path: two half-passes (one head each), LDS re-transpose.
            u16* T = SM;                      // [64][136] u16 = 17.4 KB
#pragma unroll
            for (int p = 0; p < 2; ++p) {
                __syncthreads();
                if ((wv & 1) == p) {
#pragma unroll
                    for (int j = 0; j < 4; ++j) {
                        const int cl = (j << 4) + lcol;              // d-local
                        const float bj = d.bias[bn + wn + (j << 4) + lcol];
#pragma unroll
                        for (int i = 0; i < 4; ++i) {
                            u16 pk[4];
#pragma unroll
                            for (int r = 0; r < 4; ++r)
                                pk[r] = f2bf_rne(acc[i][j][r] + bj);
                            *(ushort4*)(T + cl * 136 + wm + (i << 4) + quad * 4) = *(ushort4*)pk;
                        }
                    }
                }
                __syncthreads();
                const int dd = tid >> 2, nt = tid & 3;
                u16* dst = d.outH
                    + ((size_t)((bm >> 11) * NUM_HEADS + (bn >> 6) + p) * DK + dd) * NSEQ
                    + (bm & (NSEQ - 1)) + nt * 32;
                const u16* srcT = T + dd * 136 + nt * 32;
#pragma unroll
                for (int k = 0; k < 4; ++k)
                    ((uint4*)dst)[k] = *(const uint4*)(srcT + 8 * k);
            }
            return;
        }
    }

#pragma unroll
    for (int j = 0; j < 4; ++j) {
        const int col = bn + wn + (j << 4) + lcol;
        const float bj = d.bias[col];
#pragma unroll
        for (int i = 0; i < MT; ++i) {
#pragma unroll
            for (int r = 0; r < 4; ++r) {
                const int row = bm + wm + (i << 4) + quad * 4 + r;
                const float v = (acc[i][j][r] + bj) * d.scale;
                const size_t o = (size_t)row * N + col;
                if (d.mode == 0) {
                    d.outF[o] = v;
                } else {
                    u16 hi, lo;
                    split_bf16(v, hi, lo);
                    d.outH[o] = hi;
                    d.outL[o] = lo;
                }
            }
        }
    }
}

// ---------------------------------------------------------------------------
// Flash attention (R5 body, known 108 us). 128 q/block, 4 waves x 2 sets.
// S^T = K.Q^T (Q frags in regs as B-operands); per-lane softmax (q=lcol);
// P^T C-regs feed PV as B-frags (quad-consistent k-permutation); A = V^T
// frags from LDS (single RNE plane). Output: fp32 ctx (one store/frag).
// ---------------------------------------------------------------------------
__global__ __launch_bounds__(256)
void flash_attn(const u16* __restrict__ Qh_g, const u16* __restrict__ Ql_g,
                const u16* __restrict__ Kh_g, const u16* __restrict__ Kl_g,
                const u16* __restrict__ Vt_g,
                float* __restrict__ Ctx)
{
    __shared__ __align__(16) u16 Ks_h[64][72], Ks_l[64][72];
    __shared__ __align__(16) u16 Vs[64][72];    // [d][key]

    const int tid  = threadIdx.x;
    const int wv   = tid >> 6;
    const int lane = tid & 63;
    const int quad = lane >> 4;
    const int lcol = lane & 15;
    const int q0   = blockIdx.x << 7;
    const int h    = blockIdx.y;
    const int b    = blockIdx.z;
    const size_t hbase  = (size_t)b * NSEQ * D_MODEL + (size_t)h * DK;
    const size_t vtbase = (size_t)(b * NUM_HEADS + h) * DK * NSEQ;

    bf16x8 bQh[2][2], bQl[2][2];
#pragma unroll
    for (int s = 0; s < 2; ++s) {
        const u16* qh = Qh_g + hbase + (size_t)(q0 + wv * 32 + s * 16 + lcol) * D_MODEL;
        const u16* ql = Ql_g + hbase + (size_t)(q0 + wv * 32 + s * 16 + lcol) * D_MODEL;
#pragma unroll
        for (int c = 0; c < 2; ++c) {
            bQh[s][c] = *(const bf16x8*)(qh + c * 32 + quad * 8);
            bQl[s][c] = *(const bf16x8*)(ql + c * 32 + quad * 8);
        }
    }

    f32x4 Oacc[2][4];
#pragma unroll
    for (int s = 0; s < 2; ++s)
#pragma unroll
        for (int t = 0; t < 4; ++t) Oacc[s][t] = (f32x4){0.f, 0.f, 0.f, 0.f};
    float mrow[2] = {-INFINITY, -INFINITY};
    float lrow[2] = {0.f, 0.f};

    const int lr = tid >> 2;
    const int lc = (tid & 3) << 4;

    for (int kt = 0; kt < NSEQ / 64; ++kt) {
        const int k0 = kt << 6;
        __syncthreads();
        {
            const u16* skh = Kh_g + hbase + (size_t)(k0 + lr) * D_MODEL + lc;
            const u16* skl = Kl_g + hbase + (size_t)(k0 + lr) * D_MODEL + lc;
            const u16* sv  = Vt_g + vtbase + (size_t)lr * NSEQ + k0 + lc;
            *(uint4*)&Ks_h[lr][lc]     = *(const uint4*)skh;
            *(uint4*)&Ks_h[lr][lc + 8] = *(const uint4*)(skh + 8);
            *(uint4*)&Ks_l[lr][lc]     = *(const uint4*)skl;
            *(uint4*)&Ks_l[lr][lc + 8] = *(const uint4*)(skl + 8);
            *(uint4*)&Vs[lr][lc]       = *(const uint4*)sv;
            *(uint4*)&Vs[lr][lc + 8]   = *(const uint4*)(sv + 8);
        }
        __syncthreads();

        f32x4 S[2][4];
#pragma unroll
        for (int t = 0; t < 4; ++t) {
            bf16x8 aKh0 = *(const bf16x8*)&Ks_h[(t << 4) + lcol][quad * 8];
            bf16x8 aKh1 = *(const bf16x8*)&Ks_h[(t << 4) + lcol][32 + quad * 8];
            bf16x8 aKl0 = *(const bf16x8*)&Ks_l[(t << 4) + lcol][quad * 8];
            bf16x8 aKl1 = *(const bf16x8*)&Ks_l[(t << 4) + lcol][32 + quad * 8];
#pragma unroll
            for (int s = 0; s < 2; ++s) {
                f32x4 a = (f32x4){0.f, 0.f, 0.f, 0.f};
                a = __builtin_amdgcn_mfma_f32_16x16x32_bf16(aKh0, bQh[s][0], a, 0, 0, 0);
                a = __builtin_amdgcn_mfma_f32_16x16x32_bf16(aKh1, bQh[s][1], a, 0, 0, 0);
                a = __builtin_amdgcn_mfma_f32_16x16x32_bf16(aKl0, bQh[s][0], a, 0, 0, 0);
                a = __builtin_amdgcn_mfma_f32_16x16x32_bf16(aKl1, bQh[s][1], a, 0, 0, 0);
                a = __builtin_amdgcn_mfma_f32_16x16x32_bf16(aKh0, bQl[s][0], a, 0, 0, 0);
                a = __builtin_amdgcn_mfma_f32_16x16x32_bf16(aKh1, bQl[s][1], a, 0, 0, 0);
                S[s][t] = a;
            }
        }

        bf16x8 pb[2][2];
#pragma unroll
        for (int s = 0; s < 2; ++s) {
            float m16 = -INFINITY;
#pragma unroll
            for (int t = 0; t < 4; ++t)
#pragma unroll
                for (int r = 0; r < 4; ++r) m16 = fmaxf(m16, S[s][t][r]);
            m16 = fmaxf(m16, __shfl_xor(m16, 16, 64));
            m16 = fmaxf(m16, __shfl_xor(m16, 32, 64));
            const float mn = fmaxf(mrow[s], m16);
            const float alpha = __expf(mrow[s] - mn);
            mrow[s] = mn;

            float p[4][4];
            float psum = 0.f;
#pragma unroll
            for (int t = 0; t < 4; ++t)
#pragma unroll
                for (int r = 0; r < 4; ++r) {
                    const float pv = __expf(S[s][t][r] - mn);
                    p[t][r] = pv;
                    psum += pv;
                }
            psum += __shfl_xor(psum, 16, 64);
            psum += __shfl_xor(psum, 32, 64);
            lrow[s] = alpha * lrow[s] + psum;

#pragma unroll
            for (int c = 0; c < 2; ++c) {
                bf16x8 v;
#pragma unroll
                for (int r = 0; r < 4; ++r) {
                    v[r]     = (short)f2bf_rne(p[2 * c][r]);
                    v[4 + r] = (short)f2bf_rne(p[2 * c + 1][r]);
                }
                pb[s][c] = v;
            }
#pragma unroll
            for (int t = 0; t < 4; ++t)
#pragma unroll
                for (int r = 0; r < 4; ++r) Oacc[s][t][r] *= alpha;
        }

#pragma unroll
        for (int dt = 0; dt < 4; ++dt) {
            const u16* vr = &Vs[(dt << 4) + lcol][0];
#pragma unroll
            for (int c = 0; c < 2; ++c) {
                s16x4 alo = *(const s16x4*)(vr + c * 32 + quad * 4);
                s16x4 ahi = *(const s16x4*)(vr + c * 32 + 16 + quad * 4);
                bf16x8 aV;
#pragma unroll
                for (int r = 0; r < 4; ++r) { aV[r] = alo[r]; aV[4 + r] = ahi[r]; }
#pragma unroll
                for (int s = 0; s < 2; ++s)
                    Oacc[s][dt] = __builtin_amdgcn_mfma_f32_16x16x32_bf16(aV, pb[s][c], Oacc[s][dt], 0, 0, 0);
            }
        }
    }

    // epilogue: fp32 ctx, O^T rows d=16dt+4quad+r, col q=lcol
#pragma unroll
    for (int s = 0; s < 2; ++s) {
        const float inv = 1.f / lrow[s];
        const size_t base = hbase + (size_t)(q0 + wv * 32 + s * 16 + lcol) * D_MODEL;
#pragma unroll
        for (int dt = 0; dt < 4; ++dt) {
            float4 v;
            v.x = Oacc[s][dt][0] * inv;
            v.y = Oacc[s][dt][1] * inv;
            v.z = Oacc[s][dt][2] * inv;
            v.w = Oacc[s][dt][3] * inv;
            *(float4*)(Ctx + base + (dt << 4) + quad * 4) = v;
        }
    }
}

// ---------------------------------------------------------------------------
extern "C" void kernel_launch(void* const* d_in, const int* in_sizes, int n_in,
                              void* d_out, int out_size, void* d_ws, size_t ws_size,
                              hipStream_t stream)
{
    const float* query = (const float*)d_in[0];
    const float* key_i = (const float*)d_in[1];
    const float* value = (const float*)d_in[2];
    const float* w_q   = (const float*)d_in[3];
    const float* b_q   = (const float*)d_in[4];
    const float* w_k   = (const float*)d_in[5];
    const float* b_k   = (const float*)d_in[6];
    const float* w_v   = (const float*)d_in[7];
    const float* b_v   = (const float*)d_in[8];
    const float* w_o   = (const float*)d_in[9];
    const float* b_o   = (const float*)d_in[10];
    float* out = (float*)d_out;

    const size_t WE = (size_t)D_MODEL * D_MODEL;   // 1M
    const size_t AE = (size_t)MROWS * D_MODEL;     // 4M

    u16* p = (u16*)d_ws;
    u16* Wqh = p;            u16* Wql = Wqh + WE;
    u16* Wkh = Wql + WE;     u16* Wkl = Wkh + WE;
    u16* Wvh = Wkl + WE;     u16* Wvl = Wvh + WE;
    u16* Woh = Wvl + WE;     u16* Wol = Woh + WE;
    u16* Qh  = Wol + WE;     u16* Ql  = Qh + AE;
    u16* Kh  = Ql + AE;      u16* Kl  = Kh + AE;
    u16* VT  = Kl + AE;                         // 8 MB
    float* CTX = (float*)(VT + AE);             // 16 MB fp32
    // total: 16 + 32 + 8 + 16 = 72 MB

    SplitN ws4;
    ws4.src[0] = w_q; ws4.h[0] = Wqh; ws4.l[0] = Wql;
    ws4.src[1] = w_k; ws4.h[1] = Wkh; ws4.l[1] = Wkl;
    ws4.src[2] = w_v; ws4.h[2] = Wvh; ws4.l[2] = Wvl;
    ws4.src[3] = w_o; ws4.h[3] = Woh; ws4.l[3] = Wol;
    split_multi<<<dim3((unsigned)(WE / 8 / 256), 4), 256, 0, stream>>>(ws4, (int)(WE / 8));

    // QKV: batched z=3, fp32 activations in, grid x = M (XCD-coherent A reuse)
    GemmBatch gb;
    gb.d[0] = {query, Wqh, Wql, b_q, nullptr, Qh, Ql, 0.125f, 1};
    gb.d[1] = {key_i, Wkh, Wkl, b_k, nullptr, Kh, Kl, 1.0f,   1};
    gb.d[2] = {value, Wvh, Wvl, b_v, nullptr, VT,  nullptr, 1.0f, 2};
    gemm_v3<4><<<dim3(MROWS / 128, D_MODEL / 128, 3), 256, 0, stream>>>(gb, MROWS, D_MODEL, D_MODEL);

    flash_attn<<<dim3(NSEQ / 128, NUM_HEADS, BATCH), 256, 0, stream>>>(Qh, Ql, Kh, Kl, VT, CTX);

    GemmBatch go;
    go.d[0] = {CTX, Woh, Wol, b_o, out, nullptr, nullptr, 1.0f, 0};
    gemm_v3<2><<<dim3(MROWS / 64, D_MODEL / 128, 1), 256, 0, stream>>>(go, MROWS, D_MODEL, D_MODEL);
}

// Round 8
// 323.940 us; speedup vs baseline: 1.4089x; 1.4089x over previous
//
#include <hip/hip_runtime.h>
#include <math.h>

#define D_MODEL 1024
#define NUM_HEADS 16
#define DK 64
#define BATCH 2
#define NSEQ 2048
#define MROWS (BATCH * NSEQ)   // 4096

typedef __attribute__((ext_vector_type(8))) short bf16x8;
typedef __attribute__((ext_vector_type(4))) short s16x4;
typedef __attribute__((ext_vector_type(4))) float f32x4;
typedef unsigned short u16;

static __device__ __forceinline__ u16 f2bf_rne(float x) {
    union { float f; unsigned u; } v; v.f = x;
    unsigned r = v.u + 0x7fffu + ((v.u >> 16) & 1u);
    return (u16)(r >> 16);
}
static __device__ __forceinline__ void split_bf16(float x, u16& hi, u16& lo) {
    union { float f; unsigned u; } v; v.f = x;
    unsigned hb = v.u & 0xffff0000u;
    hi = (u16)(hb >> 16);
    union { unsigned u; float f; } hv; hv.u = hb;
    lo = f2bf_rne(x - hv.f);
}

#define AS1 __attribute__((address_space(1)))
#define AS3 __attribute__((address_space(3)))
static __device__ __forceinline__ void gl_lds16(const void* g, void* l) {
    __builtin_amdgcn_global_load_lds((AS1 void*)(uintptr_t)g, (AS3 void*)l, 16, 0, 0);
}

// ---------------------------------------------------------------------------
// fp32 -> split bf16 planes, up to 4 tensors per launch (blockIdx.y).
// ---------------------------------------------------------------------------
struct SplitN { const float* src[4]; u16* h[4]; u16* l[4]; };
__global__ __launch_bounds__(256)
void split_multi(SplitN args, int n8)
{
    const int w = blockIdx.y;
    const int i = blockIdx.x * 256 + threadIdx.x;
    if (i >= n8) return;
    const float* src = args.src[w];
    float4 a = ((const float4*)src)[2 * i];
    float4 b = ((const float4*)src)[2 * i + 1];
    float x[8] = {a.x, a.y, a.z, a.w, b.x, b.y, b.z, b.w};
    u16 hh[8], ll[8];
#pragma unroll
    for (int j = 0; j < 8; ++j) split_bf16(x[j], hh[j], ll[j]);
    *(uint4*)(args.h[w] + 8 * (size_t)i) = *(uint4*)hh;
    *(uint4*)(args.l[w] + 8 * (size_t)i) = *(uint4*)ll;
}

// ---------------------------------------------------------------------------
// Batched MFMA GEMM (R5-proven structure), split-bf16 3-term:
// C = (A @ W^T + bias) * scale. BM=128 BN=64 BK=64, 256 thr (4 waves 2x2),
// 16B-granule XOR swizzle on the global side of global_load_lds.
// XCD fix (R8): blockIdx.x = M-dim -> same-A blocks land on one XCD.
// mode 0: fp32 out. mode 1: split planes. mode 2: V -> per-head transposed
// single RNE plane Vt[b][h][d][n] via LDS re-transpose.
// ---------------------------------------------------------------------------
#define GBM 128
#define GBN 64
#define GBK 64

struct GemmDesc {
    const u16 *Ah, *Al, *Wh, *Wl;
    const float* bias;
    float* outF;
    u16 *outH, *outL;
    float scale;
    int mode;
};
struct GemmBatch { GemmDesc d[3]; };

__global__ __launch_bounds__(256)
void gemm_mfma_batch(GemmBatch batch, int M, int N, int K)
{
    __shared__ u16 SM[2 * GBM * GBK + 2 * GBN * GBK];   // 48 KB pool
    u16* As_h = SM;                       // [128][64]
    u16* As_l = SM + GBM * GBK;
    u16* Ws_h = SM + 2 * GBM * GBK;       // [64][64]
    u16* Ws_l = SM + 2 * GBM * GBK + GBN * GBK;

    const GemmDesc d = batch.d[blockIdx.z];
    const int tid  = threadIdx.x;
    const int wv   = tid >> 6, lane = tid & 63;
    const int quad = lane >> 4, lcol = lane & 15;
    const int bm = blockIdx.x * GBM, bn = blockIdx.y * GBN;   // x = M (XCD fix)
    const int wm = (wv >> 1) * 64, wn = (wv & 1) * 32;
    const int sj = lane >> 3, sg = lane & 7;
    const int sgx8 = ((sg ^ sj) << 3);

    f32x4 acc[4][2];
#pragma unroll
    for (int i = 0; i < 4; ++i)
#pragma unroll
        for (int j = 0; j < 2; ++j) acc[i][j] = (f32x4){0.f, 0.f, 0.f, 0.f};

    for (int k0 = 0; k0 < K; k0 += GBK) {
        __syncthreads();
#pragma unroll
        for (int c = 0; c < 4; ++c) {
            const int r0 = wv * 32 + c * 8;
            gl_lds16(d.Ah + (size_t)(bm + r0 + sj) * K + k0 + sgx8, As_h + r0 * GBK);
            gl_lds16(d.Al + (size_t)(bm + r0 + sj) * K + k0 + sgx8, As_l + r0 * GBK);
        }
#pragma unroll
        for (int c = 0; c < 2; ++c) {
            const int r0 = wv * 16 + c * 8;
            gl_lds16(d.Wh + (size_t)(bn + r0 + sj) * K + k0 + sgx8, Ws_h + r0 * GBK);
            gl_lds16(d.Wl + (size_t)(bn + r0 + sj) * K + k0 + sgx8, Ws_l + r0 * GBK);
        }
        __syncthreads();

#pragma unroll
        for (int hf = 0; hf < 2; ++hf) {
            const int sl = ((((hf << 2) + quad) ^ (lcol & 7)) << 3);
            bf16x8 bh[2], bl[2];
#pragma unroll
            for (int j = 0; j < 2; ++j) {
                const int rn = wn + (j << 4) + lcol;
                bh[j] = *(const bf16x8*)(Ws_h + rn * GBK + sl);
                bl[j] = *(const bf16x8*)(Ws_l + rn * GBK + sl);
            }
#pragma unroll
            for (int i = 0; i < 4; ++i) {
                const int rm = wm + (i << 4) + lcol;
                bf16x8 ah = *(const bf16x8*)(As_h + rm * GBK + sl);
                bf16x8 al = *(const bf16x8*)(As_l + rm * GBK + sl);
#pragma unroll
                for (int j = 0; j < 2; ++j) {
                    acc[i][j] = __builtin_amdgcn_mfma_f32_16x16x32_bf16(ah, bh[j], acc[i][j], 0, 0, 0);
                    acc[i][j] = __builtin_amdgcn_mfma_f32_16x16x32_bf16(al, bh[j], acc[i][j], 0, 0, 0);
                    acc[i][j] = __builtin_amdgcn_mfma_f32_16x16x32_bf16(ah, bl[j], acc[i][j], 0, 0, 0);
                }
            }
        }
    }

    if (d.mode == 2) {
        // V path: re-transpose via LDS, write Vt[b][h][d][n] single RNE plane.
        const int TS = 136;
        u16* T = SM;
        __syncthreads();
#pragma unroll
        for (int j = 0; j < 2; ++j) {
            const int cl = wn + (j << 4) + lcol;       // d-local 0..63
            const float bj = d.bias[bn + cl];
#pragma unroll
            for (int i = 0; i < 4; ++i) {
                const int r0 = wm + (i << 4) + quad * 4;
                u16 pk[4];
#pragma unroll
                for (int r = 0; r < 4; ++r) pk[r] = f2bf_rne(acc[i][j][r] + bj);
                *(ushort4*)(T + cl * TS + r0) = *(ushort4*)pk;
            }
        }
        __syncthreads();
        const int dd = tid >> 2, pt = tid & 3;
        const int bidx = bm >> 11, hh = bn >> 6;
        u16* dst = d.outH + ((size_t)(bidx * NUM_HEADS + hh) * DK + dd) * NSEQ
                 + (bm & (NSEQ - 1)) + pt * 32;
        const u16* src = T + dd * TS + pt * 32;
#pragma unroll
        for (int k = 0; k < 4; ++k)
            ((uint4*)dst)[k] = *(const uint4*)(src + 8 * k);
        return;
    }

#pragma unroll
    for (int j = 0; j < 2; ++j) {
        const int col = bn + wn + (j << 4) + lcol;
        const float bj = d.bias[col];
#pragma unroll
        for (int i = 0; i < 4; ++i) {
#pragma unroll
            for (int r = 0; r < 4; ++r) {
                const int row = bm + wm + (i << 4) + quad * 4 + r;
                const float v = (acc[i][j][r] + bj) * d.scale;
                const size_t o = (size_t)row * N + col;
                if (d.mode == 0) {
                    d.outF[o] = v;
                } else {
                    u16 hi, lo;
                    split_bf16(v, hi, lo);
                    d.outH[o] = hi;
                    d.outL[o] = lo;
                }
            }
        }
    }
}

// ---------------------------------------------------------------------------
// Flash attention (R5 body). 128 q/block, 4 waves x (2 sets of 16 q).
// S^T = K·Q^T; per-lane softmax (q=lcol); P^T C-regs feed PV directly as
// B-frags (quad-consistent k-permutation); A = V^T frags from LDS.
// XCD fix (R8): blockIdx.x = head, blockIdx.y = q-tile -> the 16 q-blocks
// sharing one head's K/V planes (3 MB, L2-sized) land on one XCD.
// ---------------------------------------------------------------------------
__global__ __launch_bounds__(256)
void flash_attn(const u16* __restrict__ Qh_g, const u16* __restrict__ Ql_g,
                const u16* __restrict__ Kh_g, const u16* __restrict__ Kl_g,
                const u16* __restrict__ Vt_g,
                u16* __restrict__ Ch_g, u16* __restrict__ Cl_g)
{
    __shared__ __align__(16) u16 Ks_h[64][72], Ks_l[64][72];
    __shared__ __align__(16) u16 Vs[64][72];    // [d][key]

    const int tid  = threadIdx.x;
    const int wv   = tid >> 6;
    const int lane = tid & 63;
    const int quad = lane >> 4;
    const int lcol = lane & 15;
    const int h    = blockIdx.x;        // XCD fix: head is the fast index
    const int q0   = blockIdx.y << 7;
    const int b    = blockIdx.z;
    const size_t hbase  = (size_t)b * NSEQ * D_MODEL + (size_t)h * DK;
    const size_t vtbase = (size_t)(b * NUM_HEADS + h) * DK * NSEQ;

    bf16x8 bQh[2][2], bQl[2][2];
#pragma unroll
    for (int s = 0; s < 2; ++s) {
        const u16* qh = Qh_g + hbase + (size_t)(q0 + wv * 32 + s * 16 + lcol) * D_MODEL;
        const u16* ql = Ql_g + hbase + (size_t)(q0 + wv * 32 + s * 16 + lcol) * D_MODEL;
#pragma unroll
        for (int c = 0; c < 2; ++c) {
            bQh[s][c] = *(const bf16x8*)(qh + c * 32 + quad * 8);
            bQl[s][c] = *(const bf16x8*)(ql + c * 32 + quad * 8);
        }
    }

    f32x4 Oacc[2][4];
#pragma unroll
    for (int s = 0; s < 2; ++s)
#pragma unroll
        for (int t = 0; t < 4; ++t) Oacc[s][t] = (f32x4){0.f, 0.f, 0.f, 0.f};
    float mrow[2] = {-INFINITY, -INFINITY};
    float lrow[2] = {0.f, 0.f};

    const int lr = tid >> 2;
    const int lc = (tid & 3) << 4;

    for (int kt = 0; kt < NSEQ / 64; ++kt) {
        const int k0 = kt << 6;
        __syncthreads();
        {
            const u16* skh = Kh_g + hbase + (size_t)(k0 + lr) * D_MODEL + lc;
            const u16* skl = Kl_g + hbase + (size_t)(k0 + lr) * D_MODEL + lc;
            const u16* sv  = Vt_g + vtbase + (size_t)lr * NSEQ + k0 + lc;
            *(uint4*)&Ks_h[lr][lc]     = *(const uint4*)skh;
            *(uint4*)&Ks_h[lr][lc + 8] = *(const uint4*)(skh + 8);
            *(uint4*)&Ks_l[lr][lc]     = *(const uint4*)skl;
            *(uint4*)&Ks_l[lr][lc + 8] = *(const uint4*)(skl + 8);
            *(uint4*)&Vs[lr][lc]       = *(const uint4*)sv;
            *(uint4*)&Vs[lr][lc + 8]   = *(const uint4*)(sv + 8);
        }
        __syncthreads();

        f32x4 S[2][4];
#pragma unroll
        for (int t = 0; t < 4; ++t) {
            bf16x8 aKh0 = *(const bf16x8*)&Ks_h[(t << 4) + lcol][quad * 8];
            bf16x8 aKh1 = *(const bf16x8*)&Ks_h[(t << 4) + lcol][32 + quad * 8];
            bf16x8 aKl0 = *(const bf16x8*)&Ks_l[(t << 4) + lcol][quad * 8];
            bf16x8 aKl1 = *(const bf16x8*)&Ks_l[(t << 4) + lcol][32 + quad * 8];
#pragma unroll
            for (int s = 0; s < 2; ++s) {
                f32x4 a = (f32x4){0.f, 0.f, 0.f, 0.f};
                a = __builtin_amdgcn_mfma_f32_16x16x32_bf16(aKh0, bQh[s][0], a, 0, 0, 0);
                a = __builtin_amdgcn_mfma_f32_16x16x32_bf16(aKh1, bQh[s][1], a, 0, 0, 0);
                a = __builtin_amdgcn_mfma_f32_16x16x32_bf16(aKl0, bQh[s][0], a, 0, 0, 0);
                a = __builtin_amdgcn_mfma_f32_16x16x32_bf16(aKl1, bQh[s][1], a, 0, 0, 0);
                a = __builtin_amdgcn_mfma_f32_16x16x32_bf16(aKh0, bQl[s][0], a, 0, 0, 0);
                a = __builtin_amdgcn_mfma_f32_16x16x32_bf16(aKh1, bQl[s][1], a, 0, 0, 0);
                S[s][t] = a;
            }
        }

        bf16x8 pb[2][2];
#pragma unroll
        for (int s = 0; s < 2; ++s) {
            float m16 = -INFINITY;
#pragma unroll
            for (int t = 0; t < 4; ++t)
#pragma unroll
                for (int r = 0; r < 4; ++r) m16 = fmaxf(m16, S[s][t][r]);
            m16 = fmaxf(m16, __shfl_xor(m16, 16, 64));
            m16 = fmaxf(m16, __shfl_xor(m16, 32, 64));
            const float mn = fmaxf(mrow[s], m16);
            const float alpha = __expf(mrow[s] - mn);
            mrow[s] = mn;

            float p[4][4];
            float psum = 0.f;
#pragma unroll
            for (int t = 0; t < 4; ++t)
#pragma unroll
                for (int r = 0; r < 4; ++r) {
                    const float pv = __expf(S[s][t][r] - mn);
                    p[t][r] = pv;
                    psum += pv;
                }
            psum += __shfl_xor(psum, 16, 64);
            psum += __shfl_xor(psum, 32, 64);
            lrow[s] = alpha * lrow[s] + psum;

#pragma unroll
            for (int c = 0; c < 2; ++c) {
                bf16x8 v;
#pragma unroll
                for (int r = 0; r < 4; ++r) {
                    v[r]     = (short)f2bf_rne(p[2 * c][r]);
                    v[4 + r] = (short)f2bf_rne(p[2 * c + 1][r]);
                }
                pb[s][c] = v;
            }
#pragma unroll
            for (int t = 0; t < 4; ++t)
#pragma unroll
                for (int r = 0; r < 4; ++r) Oacc[s][t][r] *= alpha;
        }

#pragma unroll
        for (int dt = 0; dt < 4; ++dt) {
            const u16* vr = &Vs[(dt << 4) + lcol][0];
#pragma unroll
            for (int c = 0; c < 2; ++c) {
                s16x4 alo = *(const s16x4*)(vr + c * 32 + quad * 4);
                s16x4 ahi = *(const s16x4*)(vr + c * 32 + 16 + quad * 4);
                bf16x8 aV;
#pragma unroll
                for (int r = 0; r < 4; ++r) { aV[r] = alo[r]; aV[4 + r] = ahi[r]; }
#pragma unroll
                for (int s = 0; s < 2; ++s)
                    Oacc[s][dt] = __builtin_amdgcn_mfma_f32_16x16x32_bf16(aV, pb[s][c], Oacc[s][dt], 0, 0, 0);
            }
        }
    }

#pragma unroll
    for (int s = 0; s < 2; ++s) {
        const float inv = 1.f / lrow[s];
        const size_t base = hbase + (size_t)(q0 + wv * 32 + s * 16 + lcol) * D_MODEL;
#pragma unroll
        for (int dt = 0; dt < 4; ++dt) {
            u16 hv[4], lv[4];
#pragma unroll
            for (int r = 0; r < 4; ++r)
                split_bf16(Oacc[s][dt][r] * inv, hv[r], lv[r]);
            const size_t o = base + (dt << 4) + quad * 4;
            *(ushort4*)(Ch_g + o) = *(ushort4*)hv;
            *(ushort4*)(Cl_g + o) = *(ushort4*)lv;
        }
    }
}

// ---------------------------------------------------------------------------
extern "C" void kernel_launch(void* const* d_in, const int* in_sizes, int n_in,
                              void* d_out, int out_size, void* d_ws, size_t ws_size,
                              hipStream_t stream)
{
    const float* query = (const float*)d_in[0];
    const float* key_i = (const float*)d_in[1];
    const float* value = (const float*)d_in[2];
    const float* w_q   = (const float*)d_in[3];
    const float* b_q   = (const float*)d_in[4];
    const float* w_k   = (const float*)d_in[5];
    const float* b_k   = (const float*)d_in[6];
    const float* w_v   = (const float*)d_in[7];
    const float* b_v   = (const float*)d_in[8];
    const float* w_o   = (const float*)d_in[9];
    const float* b_o   = (const float*)d_in[10];
    float* out = (float*)d_out;

    const size_t WE = (size_t)D_MODEL * D_MODEL;   // 1M
    const size_t AE = (size_t)MROWS * D_MODEL;     // 4M

    u16* p = (u16*)d_ws;
    u16* Wqh = p;            u16* Wql = Wqh + WE;
    u16* Wkh = Wql + WE;     u16* Wkl = Wkh + WE;
    u16* Wvh = Wkl + WE;     u16* Wvl = Wvh + WE;
    u16* Woh = Wvl + WE;     u16* Wol = Woh + WE;
    u16* base = Wol + WE;

    SplitN ws4;
    ws4.src[0] = w_q; ws4.h[0] = Wqh; ws4.l[0] = Wql;
    ws4.src[1] = w_k; ws4.h[1] = Wkh; ws4.l[1] = Wkl;
    ws4.src[2] = w_v; ws4.h[2] = Wvh; ws4.l[2] = Wvl;
    ws4.src[3] = w_o; ws4.h[3] = Woh; ws4.l[3] = Wol;
    split_multi<<<dim3((unsigned)(WE / 8 / 256), 4), 256, 0, stream>>>(ws4, (int)(WE / 8));

    const float qscale = 0.125f;
    // XCD-aware grids: x = dimension whose blocks SHARE data.
    dim3 fgrid(NUM_HEADS, NSEQ / 128, BATCH);        // (16,16,2), x = head
    dim3 ggrid3(MROWS / GBM, D_MODEL / GBN, 3);      // (32,16,3), x = M
    dim3 ggrid1(MROWS / GBM, D_MODEL / GBN, 1);      // (32,16,1), x = M
    const int an8 = (int)(AE / 8);

    const size_t fused_bytes = 2 * (8 * WE + 11 * AE);   // 104 MB
    if (ws_size >= fused_bytes) {
        u16* INqh = base;          u16* INql = INqh + AE;
        u16* INkh = INql + AE;     u16* INkl = INkh + AE;
        u16* INvh = INkl + AE;     u16* INvl = INvh + AE;
        u16* Qph  = INvl + AE;     u16* Qpl  = Qph + AE;
        u16* Kph  = Qpl + AE;      u16* Kpl  = Kph + AE;
        u16* VT   = Kpl + AE;
        u16* Ch   = INqh;          u16* Cl   = INql;    // alias, dead after QKV

        SplitN as3;
        as3.src[0] = query; as3.h[0] = INqh; as3.l[0] = INql;
        as3.src[1] = key_i; as3.h[1] = INkh; as3.l[1] = INkl;
        as3.src[2] = value; as3.h[2] = INvh; as3.l[2] = INvl;
        as3.src[3] = query; as3.h[3] = INqh; as3.l[3] = INql;  // unused
        split_multi<<<dim3((unsigned)(AE / 8 / 256), 3), 256, 0, stream>>>(as3, an8);

        GemmBatch gb;
        gb.d[0] = {INqh, INql, Wqh, Wql, b_q, nullptr, Qph, Qpl, qscale, 1};
        gb.d[1] = {INkh, INkl, Wkh, Wkl, b_k, nullptr, Kph, Kpl, 1.0f,   1};
        gb.d[2] = {INvh, INvl, Wvh, Wvl, b_v, nullptr, VT,  nullptr, 1.0f, 2};
        gemm_mfma_batch<<<ggrid3, 256, 0, stream>>>(gb, MROWS, D_MODEL, D_MODEL);

        flash_attn<<<fgrid, 256, 0, stream>>>(Qph, Qpl, Kph, Kpl, VT, Ch, Cl);

        GemmBatch go;
        go.d[0] = {Ch, Cl, Woh, Wol, b_o, out, nullptr, nullptr, 1.0f, 0};
        gemm_mfma_batch<<<ggrid1, 256, 0, stream>>>(go, MROWS, D_MODEL, D_MODEL);
    } else {
        u16* INh = base;           u16* INl = INh + AE;
        u16* Qph = INl + AE;       u16* Qpl = Qph + AE;
        u16* Kph = Qpl + AE;       u16* Kpl = Kph + AE;
        u16* VT  = Kpl + AE;
        u16* Ch  = INh;            u16* Cl  = INl;

        SplitN s1;
        s1.src[0] = query; s1.h[0] = INh; s1.l[0] = INl;
        s1.src[1] = s1.src[2] = s1.src[3] = query;
        s1.h[1] = s1.h[2] = s1.h[3] = INh; s1.l[1] = s1.l[2] = s1.l[3] = INl;

        GemmBatch g;
        s1.src[0] = query;
        split_multi<<<dim3((unsigned)(AE / 8 / 256), 1), 256, 0, stream>>>(s1, an8);
        g.d[0] = {INh, INl, Wqh, Wql, b_q, nullptr, Qph, Qpl, qscale, 1};
        gemm_mfma_batch<<<ggrid1, 256, 0, stream>>>(g, MROWS, D_MODEL, D_MODEL);

        s1.src[0] = key_i;
        split_multi<<<dim3((unsigned)(AE / 8 / 256), 1), 256, 0, stream>>>(s1, an8);
        g.d[0] = {INh, INl, Wkh, Wkl, b_k, nullptr, Kph, Kpl, 1.0f, 1};
        gemm_mfma_batch<<<ggrid1, 256, 0, stream>>>(g, MROWS, D_MODEL, D_MODEL);

        s1.src[0] = value;
        split_multi<<<dim3((unsigned)(AE / 8 / 256), 1), 256, 0, stream>>>(s1, an8);
        g.d[0] = {INh, INl, Wvh, Wvl, b_v, nullptr, VT, nullptr, 1.0f, 2};
        gemm_mfma_batch<<<ggrid1, 256, 0, stream>>>(g, MROWS, D_MODEL, D_MODEL);

        flash_attn<<<fgrid, 256, 0, stream>>>(Qph, Qpl, Kph, Kpl, VT, Ch, Cl);

        g.d[0] = {Ch, Cl, Woh, Wol, b_o, out, nullptr, nullptr, 1.0f, 0};
        gemm_mfma_batch<<<ggrid1, 256, 0, stream>>>(g, MROWS, D_MODEL, D_MODEL);
    }
}